// Round 18
// baseline (733.797 us; speedup 1.0000x reference)
//
#include <hip/hip_runtime.h>
#include <hip/hip_bf16.h>
#include <math.h>

#define NTOK   16384
#define DMODEL 512
#define NHEAD  8
#define DHEAD  64
#define NEXP   8
#define DFF    2048
#define SEQ    1024
#define BATCH  16
#define CAPE   2560
#define LNEPS  1e-5f

typedef __attribute__((ext_vector_type(8))) short bf16x8;
typedef __attribute__((ext_vector_type(4))) float f32x4;

__device__ inline ushort f2bf(float f) {
  union { float f; unsigned int u; } v; v.f = f;
  unsigned int u = v.u + 0x7fffu + ((v.u >> 16) & 1u);
  return (ushort)(u >> 16);
}
__device__ inline float bf2f(ushort h) {
  union { unsigned int u; float f; } v; v.u = ((unsigned)h) << 16; return v.f;
}
__device__ inline unsigned fbits(float x) { union { float f; unsigned u; } v; v.f = x; return v.u; }
__device__ inline float fval(unsigned u) { union { unsigned u; float f; } v; v.u = u; return v.f; }
// truncation 3-split: x == hi16(u0) + hi16(u1) + hi16(u2) (as bf16 planes), error ~2^-22|x|
__device__ __forceinline__ void tsplit3(float x, unsigned& u0, unsigned& u1, unsigned& u2) {
  u0 = fbits(x);
  float r1 = x - fval(u0 & 0xFFFF0000u);
  u1 = fbits(r1);
  float r2 = r1 - fval(u1 & 0xFFFF0000u);
  u2 = fbits(r2);
}
__device__ __forceinline__ unsigned packhi(unsigned lo, unsigned hi) {
  return (hi & 0xFFFF0000u) | (lo >> 16);
}
// async global->LDS, 16B per lane; lds base must be wave-uniform
__device__ __forceinline__ void gload_lds16(const void* g, void* l) {
  __builtin_amdgcn_global_load_lds(
      (const __attribute__((address_space(1))) unsigned int*)g,
      (__attribute__((address_space(3))) unsigned int*)l, 16, 0, 0);
}

// ---------------- W pre-split: in W[R=K][C=N] fp32 -> out[3][N][K] bf16 planes
__global__ __launch_bounds__(256) void wsplit3_kernel(
    const float* __restrict__ in, ushort* __restrict__ out, int R, int C) {
  __shared__ float T[64][65];
  int c0 = blockIdx.x * 64, r0 = blockIdx.y * 64;
  int tid = threadIdx.x;
  size_t plane = (size_t)R * C;
#pragma unroll
  for (int i = 0; i < 4; ++i) {
    int idx = tid + i * 256;
    int r = idx >> 4, c4 = (idx & 15) * 4;
    float4 t = *reinterpret_cast<const float4*>(&in[(size_t)(r0 + r) * C + c0 + c4]);
    T[r][c4] = t.x; T[r][c4 + 1] = t.y; T[r][c4 + 2] = t.z; T[r][c4 + 3] = t.w;
  }
  __syncthreads();
  int n = tid >> 2, kg = (tid & 3) * 16;
  ushort p0[16], p1[16], p2[16];
#pragma unroll
  for (int j = 0; j < 16; ++j) {
    unsigned u0, u1, u2;
    tsplit3(T[kg + j][n], u0, u1, u2);
    p0[j] = (ushort)(u0 >> 16);
    p1[j] = (ushort)(u1 >> 16);
    p2[j] = (ushort)(u2 >> 16);
  }
  size_t ob = (size_t)(c0 + n) * R + r0 + kg;
  *reinterpret_cast<uint4*>(&out[ob])                  = *reinterpret_cast<uint4*>(&p0[0]);
  *reinterpret_cast<uint4*>(&out[ob + 8])              = *reinterpret_cast<uint4*>(&p0[8]);
  *reinterpret_cast<uint4*>(&out[plane + ob])          = *reinterpret_cast<uint4*>(&p1[0]);
  *reinterpret_cast<uint4*>(&out[plane + ob + 8])      = *reinterpret_cast<uint4*>(&p1[8]);
  *reinterpret_cast<uint4*>(&out[2 * plane + ob])      = *reinterpret_cast<uint4*>(&p2[0]);
  *reinterpret_cast<uint4*>(&out[2 * plane + ob + 8])  = *reinterpret_cast<uint4*>(&p2[8]);
}

// ---------------- fp32-equivalent proj GEMM via 6-term split-3 bf16 MFMA.
// 256x128 tile, 8 waves (wave grid 4m x 2n); per-wave structure unchanged.
__global__ __launch_bounds__(512) void gemm_split3_kernel(
    const float* __restrict__ A, const ushort* __restrict__ W3,
    const float* __restrict__ bias, float* __restrict__ Co,
    int M, int K, int N) {
  __shared__ __align__(16) ushort As3[3][256][32];
  __shared__ __align__(16) ushort Bs3[3][128][32];
  int tid = threadIdx.x;
  int wave = tid >> 6, lane = tid & 63;
  int wm = wave >> 1, wn = wave & 1;
  int c16 = lane & 15, g = lane >> 4;
  int row0 = blockIdx.y * 256, col0 = blockIdx.x * 128;
  size_t plane = (size_t)K * N;
  int ar = tid >> 1, ah = tid & 1;
  int rloc = lane >> 2;
  int bseg = ((lane & 3) ^ (rloc & 3)) * 8;
  int q0s = (ah * 2) ^ (ar & 3);
  int q1s = (ah * 2 + 1) ^ (ar & 3);
  int ksw = (g ^ (c16 & 3)) * 8;
  f32x4 acc[4][4] = {};

  for (int k0 = 0; k0 < K; k0 += 32) {
    // B: 3 planes x 128 rows; each wave loads 16 rows of each plane
#pragma unroll
    for (int s = 0; s < 3; ++s) {
      int rowb = wave * 16;
      gload_lds16(W3 + (size_t)s * plane + (size_t)(col0 + rowb + rloc) * K + k0 + bseg,
                  &Bs3[s][rowb][0]);
    }
    // A: 16 fp32/thread -> trunc-split -> swizzled LDS (ar covers 0..255)
    {
      const float* ap = A + (size_t)(row0 + ar) * K + k0 + ah * 16;
      float xs[16];
#pragma unroll
      for (int i = 0; i < 4; ++i) {
        float4 t = *reinterpret_cast<const float4*>(ap + i * 4);
        xs[i * 4] = t.x; xs[i * 4 + 1] = t.y; xs[i * 4 + 2] = t.z; xs[i * 4 + 3] = t.w;
      }
      ushort p0[16], p1[16], p2[16];
#pragma unroll
      for (int j = 0; j < 16; ++j) {
        unsigned u0, u1, u2;
        tsplit3(xs[j], u0, u1, u2);
        p0[j] = (ushort)(u0 >> 16);
        p1[j] = (ushort)(u1 >> 16);
        p2[j] = (ushort)(u2 >> 16);
      }
      *reinterpret_cast<uint4*>(&As3[0][ar][q0s * 8]) = *reinterpret_cast<uint4*>(&p0[0]);
      *reinterpret_cast<uint4*>(&As3[0][ar][q1s * 8]) = *reinterpret_cast<uint4*>(&p0[8]);
      *reinterpret_cast<uint4*>(&As3[1][ar][q0s * 8]) = *reinterpret_cast<uint4*>(&p1[0]);
      *reinterpret_cast<uint4*>(&As3[1][ar][q1s * 8]) = *reinterpret_cast<uint4*>(&p1[8]);
      *reinterpret_cast<uint4*>(&As3[2][ar][q0s * 8]) = *reinterpret_cast<uint4*>(&p2[0]);
      *reinterpret_cast<uint4*>(&As3[2][ar][q1s * 8]) = *reinterpret_cast<uint4*>(&p2[8]);
    }
    __syncthreads();
    bf16x8 bfr[4][3];
#pragma unroll
    for (int nt = 0; nt < 4; ++nt)
#pragma unroll
      for (int s = 0; s < 3; ++s)
        bfr[nt][s] = *reinterpret_cast<bf16x8*>(&Bs3[s][wn * 64 + nt * 16 + c16][ksw]);
#pragma unroll
    for (int mt = 0; mt < 4; ++mt) {
      int arow = wm * 64 + mt * 16 + c16;
      bf16x8 a0 = *reinterpret_cast<bf16x8*>(&As3[0][arow][ksw]);
      bf16x8 a1 = *reinterpret_cast<bf16x8*>(&As3[1][arow][ksw]);
      bf16x8 a2 = *reinterpret_cast<bf16x8*>(&As3[2][arow][ksw]);
#pragma unroll
      for (int nt = 0; nt < 4; ++nt) {
        acc[mt][nt] = __builtin_amdgcn_mfma_f32_16x16x32_bf16(a0, bfr[nt][0], acc[mt][nt], 0, 0, 0);
        acc[mt][nt] = __builtin_amdgcn_mfma_f32_16x16x32_bf16(a0, bfr[nt][1], acc[mt][nt], 0, 0, 0);
        acc[mt][nt] = __builtin_amdgcn_mfma_f32_16x16x32_bf16(a1, bfr[nt][0], acc[mt][nt], 0, 0, 0);
        acc[mt][nt] = __builtin_amdgcn_mfma_f32_16x16x32_bf16(a1, bfr[nt][1], acc[mt][nt], 0, 0, 0);
        acc[mt][nt] = __builtin_amdgcn_mfma_f32_16x16x32_bf16(a0, bfr[nt][2], acc[mt][nt], 0, 0, 0);
        acc[mt][nt] = __builtin_amdgcn_mfma_f32_16x16x32_bf16(a2, bfr[nt][0], acc[mt][nt], 0, 0, 0);
      }
    }
    __syncthreads();
  }
  int rowq = g * 4;
#pragma unroll
  for (int mt = 0; mt < 4; ++mt) {
#pragma unroll
    for (int i = 0; i < 4; ++i) {
      int r = row0 + wm * 64 + mt * 16 + rowq + i;
#pragma unroll
      for (int nt = 0; nt < 4; ++nt) {
        int c = col0 + wn * 64 + nt * 16 + c16;
        Co[(size_t)r * N + c] = acc[mt][nt][i] + bias[c];
      }
    }
  }
}

// ---------------- flash attention, fp32-equivalent via trunc-split bf16 MFMA.
// 512 threads = 8 waves; q-tile 256 rows as TWO 128-row halves sharing staged K/V
// AND sharing kf/vf fragment loads (pfA captured in regs before Ps reuse).
#define KC 32
__global__ __launch_bounds__(512, 4) void attn_kernel(
    const float* __restrict__ q, const float* __restrict__ k,
    const float* __restrict__ v, float* __restrict__ ctx) {
  __shared__ short Ks[3][KC][72];    // [split][key][dim]
  __shared__ short Vt[3][64][40];    // [split][dim][key]
  __shared__ short Ps[3][128][40];   // [split][qrow(half)][key] — reused A then B
  int tid = threadIdx.x;
  int w = tid >> 6, lane = tid & 63;
  int g = lane >> 4, c16 = lane & 15;
  int bid = blockIdx.x;
  int qt = bid & 3, h = (bid >> 2) & 7, b = bid >> 5;
  int q0 = qt * 256;
  size_t basebh = (size_t)b * SEQ * DMODEL + (size_t)h * DHEAD;

  // ---- Q fragments for both halves (scaled 1/8), trunc-split
  bf16x8 qfA[2][3], qfB[2][3];
  {
    int qrowA = q0 + w * 16 + c16;
    int qrowB = qrowA + 128;
    const float* qpA = &q[basebh + (size_t)qrowA * DMODEL];
    const float* qpB = &q[basebh + (size_t)qrowB * DMODEL];
#pragma unroll
    for (int ks = 0; ks < 2; ++ks) {
      int d0 = ks * 32 + g * 8;
      float4 fa = *reinterpret_cast<const float4*>(qpA + d0);
      float4 fb = *reinterpret_cast<const float4*>(qpA + d0 + 4);
      float xs[8] = {fa.x, fa.y, fa.z, fa.w, fb.x, fb.y, fb.z, fb.w};
#pragma unroll
      for (int j = 0; j < 8; ++j) {
        unsigned u0, u1, u2;
        tsplit3(xs[j] * 0.125f, u0, u1, u2);
        qfA[ks][0][j] = (short)(u0 >> 16);
        qfA[ks][1][j] = (short)(u1 >> 16);
        qfA[ks][2][j] = (short)(u2 >> 16);
      }
      float4 fc = *reinterpret_cast<const float4*>(qpB + d0);
      float4 fd = *reinterpret_cast<const float4*>(qpB + d0 + 4);
      float ys[8] = {fc.x, fc.y, fc.z, fc.w, fd.x, fd.y, fd.z, fd.w};
#pragma unroll
      for (int j = 0; j < 8; ++j) {
        unsigned u0, u1, u2;
        tsplit3(ys[j] * 0.125f, u0, u1, u2);
        qfB[ks][0][j] = (short)(u0 >> 16);
        qfB[ks][1][j] = (short)(u1 >> 16);
        qfB[ks][2][j] = (short)(u2 >> 16);
      }
    }
  }

  f32x4 OA[4] = {}, OB[4] = {};
  float lrowA[4] = {}, lrowB[4] = {};

  int skey = tid >> 4, sd0 = (tid & 15) * 4;        // K: key, 4 dims
  int vd2 = (tid & 31) * 2, kp2 = (tid >> 5) * 2;   // V: 2 dims x 2 keys

  for (int kc = 0; kc < SEQ; kc += KC) {
    // ---- stage K chunk (4 elems/thread), trunc-split, uint2 writes
    {
      const float* kp = &k[basebh + (size_t)(kc + skey) * DMODEL + sd0];
      float4 fa = *reinterpret_cast<const float4*>(kp);
      float xs[4] = {fa.x, fa.y, fa.z, fa.w};
      unsigned u[3][4];
#pragma unroll
      for (int j = 0; j < 4; ++j) tsplit3(xs[j], u[0][j], u[1][j], u[2][j]);
#pragma unroll
      for (int s = 0; s < 3; ++s) {
        uint2 pk;
        pk.x = packhi(u[s][0], u[s][1]);
        pk.y = packhi(u[s][2], u[s][3]);
        *reinterpret_cast<uint2*>(&Ks[s][skey][sd0]) = pk;
      }
    }
    // ---- stage V chunk transposed (4 elems/thread)
    {
      const float* vpa = &v[basebh + (size_t)(kc + kp2) * DMODEL + vd2];
      float2 va = *reinterpret_cast<const float2*>(vpa);
      float2 vb2 = *reinterpret_cast<const float2*>(vpa + DMODEL);
      unsigned a0, a1, a2, b0, b1, b2;
      tsplit3(va.x, a0, a1, a2);
      tsplit3(vb2.x, b0, b1, b2);
      *reinterpret_cast<unsigned*>(&Vt[0][vd2][kp2]) = packhi(a0, b0);
      *reinterpret_cast<unsigned*>(&Vt[1][vd2][kp2]) = packhi(a1, b1);
      *reinterpret_cast<unsigned*>(&Vt[2][vd2][kp2]) = packhi(a2, b2);
      tsplit3(va.y, a0, a1, a2);
      tsplit3(vb2.y, b0, b1, b2);
      *reinterpret_cast<unsigned*>(&Vt[0][vd2 + 1][kp2]) = packhi(a0, b0);
      *reinterpret_cast<unsigned*>(&Vt[1][vd2 + 1][kp2]) = packhi(a1, b1);
      *reinterpret_cast<unsigned*>(&Vt[2][vd2 + 1][kp2]) = packhi(a2, b2);
    }
    __syncthreads();

    // ---- merged QK^T: one kf load feeds both halves
    f32x4 SA[2] = {}, SB[2] = {};
#pragma unroll
    for (int ks = 0; ks < 2; ++ks) {
      bf16x8 kf[2][3];
#pragma unroll
      for (int nt = 0; nt < 2; ++nt)
#pragma unroll
        for (int s = 0; s < 3; ++s)
          kf[nt][s] = *reinterpret_cast<bf16x8*>(&Ks[s][nt * 16 + c16][ks * 32 + g * 8]);
#pragma unroll
      for (int nt = 0; nt < 2; ++nt) {
        SA[nt] = __builtin_amdgcn_mfma_f32_16x16x32_bf16(qfA[ks][0], kf[nt][0], SA[nt], 0, 0, 0);
        SA[nt] = __builtin_amdgcn_mfma_f32_16x16x32_bf16(qfA[ks][0], kf[nt][1], SA[nt], 0, 0, 0);
        SA[nt] = __builtin_amdgcn_mfma_f32_16x16x32_bf16(qfA[ks][1], kf[nt][0], SA[nt], 0, 0, 0);
        SA[nt] = __builtin_amdgcn_mfma_f32_16x16x32_bf16(qfA[ks][1], kf[nt][1], SA[nt], 0, 0, 0);
        SA[nt] = __builtin_amdgcn_mfma_f32_16x16x32_bf16(qfA[ks][0], kf[nt][2], SA[nt], 0, 0, 0);
        SA[nt] = __builtin_amdgcn_mfma_f32_16x16x32_bf16(qfA[ks][2], kf[nt][0], SA[nt], 0, 0, 0);
        SB[nt] = __builtin_amdgcn_mfma_f32_16x16x32_bf16(qfB[ks][0], kf[nt][0], SB[nt], 0, 0, 0);
        SB[nt] = __builtin_amdgcn_mfma_f32_16x16x32_bf16(qfB[ks][0], kf[nt][1], SB[nt], 0, 0, 0);
        SB[nt] = __builtin_amdgcn_mfma_f32_16x16x32_bf16(qfB[ks][1], kf[nt][0], SB[nt], 0, 0, 0);
        SB[nt] = __builtin_amdgcn_mfma_f32_16x16x32_bf16(qfB[ks][1], kf[nt][1], SB[nt], 0, 0, 0);
        SB[nt] = __builtin_amdgcn_mfma_f32_16x16x32_bf16(qfB[ks][0], kf[nt][2], SB[nt], 0, 0, 0);
        SB[nt] = __builtin_amdgcn_mfma_f32_16x16x32_bf16(qfB[ks][2], kf[nt][0], SB[nt], 0, 0, 0);
      }
    }

    // ---- softmax A + Ps store, capture pfA in regs
#pragma unroll
    for (int i = 0; i < 4; ++i) {
      float p0 = __expf(SA[0][i]);
      float p1 = __expf(SA[1][i]);
      lrowA[i] += p0 + p1;
      int prow = w * 16 + g * 4 + i;
      unsigned u0, u1, u2;
      tsplit3(p0, u0, u1, u2);
      Ps[0][prow][c16] = (short)(u0 >> 16);
      Ps[1][prow][c16] = (short)(u1 >> 16);
      Ps[2][prow][c16] = (short)(u2 >> 16);
      tsplit3(p1, u0, u1, u2);
      Ps[0][prow][c16 + 16] = (short)(u0 >> 16);
      Ps[1][prow][c16 + 16] = (short)(u1 >> 16);
      Ps[2][prow][c16 + 16] = (short)(u2 >> 16);
    }
    bf16x8 pfA0 = *reinterpret_cast<bf16x8*>(&Ps[0][w * 16 + c16][g * 8]);
    bf16x8 pfA1 = *reinterpret_cast<bf16x8*>(&Ps[1][w * 16 + c16][g * 8]);
    bf16x8 pfA2 = *reinterpret_cast<bf16x8*>(&Ps[2][w * 16 + c16][g * 8]);

    // ---- softmax B overwrites wave-private Ps rows (in-order DS pipe), capture pfB
#pragma unroll
    for (int i = 0; i < 4; ++i) {
      float p0 = __expf(SB[0][i]);
      float p1 = __expf(SB[1][i]);
      lrowB[i] += p0 + p1;
      int prow = w * 16 + g * 4 + i;
      unsigned u0, u1, u2;
      tsplit3(p0, u0, u1, u2);
      Ps[0][prow][c16] = (short)(u0 >> 16);
      Ps[1][prow][c16] = (short)(u1 >> 16);
      Ps[2][prow][c16] = (short)(u2 >> 16);
      tsplit3(p1, u0, u1, u2);
      Ps[0][prow][c16 + 16] = (short)(u0 >> 16);
      Ps[1][prow][c16 + 16] = (short)(u1 >> 16);
      Ps[2][prow][c16 + 16] = (short)(u2 >> 16);
    }
    bf16x8 pfB0 = *reinterpret_cast<bf16x8*>(&Ps[0][w * 16 + c16][g * 8]);
    bf16x8 pfB1 = *reinterpret_cast<bf16x8*>(&Ps[1][w * 16 + c16][g * 8]);
    bf16x8 pfB2 = *reinterpret_cast<bf16x8*>(&Ps[2][w * 16 + c16][g * 8]);

    // ---- shared PV: one vf load feeds both halves
#pragma unroll
    for (int dt = 0; dt < 4; ++dt) {
      bf16x8 vf[3];
#pragma unroll
      for (int s = 0; s < 3; ++s)
        vf[s] = *reinterpret_cast<bf16x8*>(&Vt[s][dt * 16 + c16][g * 8]);
      OA[dt] = __builtin_amdgcn_mfma_f32_16x16x32_bf16(pfA0, vf[0], OA[dt], 0, 0, 0);
      OA[dt] = __builtin_amdgcn_mfma_f32_16x16x32_bf16(pfA0, vf[1], OA[dt], 0, 0, 0);
      OA[dt] = __builtin_amdgcn_mfma_f32_16x16x32_bf16(pfA1, vf[0], OA[dt], 0, 0, 0);
      OA[dt] = __builtin_amdgcn_mfma_f32_16x16x32_bf16(pfA1, vf[1], OA[dt], 0, 0, 0);
      OA[dt] = __builtin_amdgcn_mfma_f32_16x16x32_bf16(pfA0, vf[2], OA[dt], 0, 0, 0);
      OA[dt] = __builtin_amdgcn_mfma_f32_16x16x32_bf16(pfA2, vf[0], OA[dt], 0, 0, 0);
      OB[dt] = __builtin_amdgcn_mfma_f32_16x16x32_bf16(pfB0, vf[0], OB[dt], 0, 0, 0);
      OB[dt] = __builtin_amdgcn_mfma_f32_16x16x32_bf16(pfB0, vf[1], OB[dt], 0, 0, 0);
      OB[dt] = __builtin_amdgcn_mfma_f32_16x16x32_bf16(pfB1, vf[0], OB[dt], 0, 0, 0);
      OB[dt] = __builtin_amdgcn_mfma_f32_16x16x32_bf16(pfB1, vf[1], OB[dt], 0, 0, 0);
      OB[dt] = __builtin_amdgcn_mfma_f32_16x16x32_bf16(pfB0, vf[2], OB[dt], 0, 0, 0);
      OB[dt] = __builtin_amdgcn_mfma_f32_16x16x32_bf16(pfB2, vf[0], OB[dt], 0, 0, 0);
    }
    __syncthreads();
  }

  // ---- epilogue: one 16-lane reduction per row per half, then normalize
#pragma unroll
  for (int i = 0; i < 4; ++i) {
    float t = lrowA[i];
#pragma unroll
    for (int off = 1; off < 16; off <<= 1) t += __shfl_xor(t, off, 64);
    float inv = 1.0f / t;
    int qrow = q0 + w * 16 + g * 4 + i;
#pragma unroll
    for (int dt = 0; dt < 4; ++dt)
      ctx[basebh + (size_t)qrow * DMODEL + dt * 16 + c16] = OA[dt][i] * inv;
  }
#pragma unroll
  for (int i = 0; i < 4; ++i) {
    float t = lrowB[i];
#pragma unroll
    for (int off = 1; off < 16; off <<= 1) t += __shfl_xor(t, off, 64);
    float inv = 1.0f / t;
    int qrow = q0 + 128 + w * 16 + g * 4 + i;
#pragma unroll
    for (int dt = 0; dt < 4; ++dt)
      ctx[basebh + (size_t)qrow * DMODEL + dt * 16 + c16] = OB[dt][i] * inv;
  }
}

// ---------------- residual + LayerNorm
__device__ inline float block_reduce_sum(float val, float* red) {
#pragma unroll
  for (int off = 32; off; off >>= 1) val += __shfl_xor(val, off, 64);
  int lane = threadIdx.x & 63, wid = threadIdx.x >> 6;
  __syncthreads();
  if (lane == 0) red[wid] = val;
  __syncthreads();
  return red[0] + red[1] + red[2] + red[3];
}

// add + LN; also emits bf16 copy of the output (for MoE GEMM1 A-operand)
__global__ __launch_bounds__(256) void add_ln_kernel(
    const float* __restrict__ a, const float* __restrict__ bsrc,
    const float* __restrict__ g, const float* __restrict__ beta,
    float* __restrict__ out, ushort* __restrict__ outbf) {
  __shared__ float red[4];
  int row = blockIdx.x, tid = threadIdx.x;
  size_t base = (size_t)row * DMODEL;
  float v0 = a[base + tid] + bsrc[base + tid];
  float v1 = a[base + tid + 256] + bsrc[base + tid + 256];
  float s = block_reduce_sum(v0 + v1, red);
  float mean = s * (1.0f / DMODEL);
  float d0 = v0 - mean, d1 = v1 - mean;
  float vs = block_reduce_sum(d0 * d0 + d1 * d1, red);
  float inv = rsqrtf(vs * (1.0f / DMODEL) + LNEPS);
  float o0 = d0 * inv * g[tid] + beta[tid];
  float o1 = d1 * inv * g[tid + 256] + beta[tid + 256];
  out[base + tid]       = o0;
  out[base + tid + 256] = o1;
  outbf[base + tid]       = f2bf(o0);
  outbf[base + tid + 256] = f2bf(o1);
}

// ---------------- router: 1 wave per token
__global__ __launch_bounds__(256) void router_kernel(
    const float* __restrict__ x1, const float* __restrict__ Wr,
    const float* __restrict__ br, int* __restrict__ routes,
    float* __restrict__ rpm_out, float* __restrict__ route_prob) {
  __shared__ float lprob[8];
  int wid = threadIdx.x >> 6, lane = threadIdx.x & 63;
  int n = blockIdx.x * 4 + wid;
  if (threadIdx.x < 8) lprob[threadIdx.x] = 0.f;
  __syncthreads();
  float p[8] = {};
  size_t base = (size_t)n * DMODEL;
  for (int d = lane; d < DMODEL; d += 64) {
    float xv = x1[base + d];
#pragma unroll
    for (int e = 0; e < 8; ++e) p[e] += xv * Wr[d * 8 + e];
  }
#pragma unroll
  for (int off = 32; off; off >>= 1)
#pragma unroll
    for (int e = 0; e < 8; ++e) p[e] += __shfl_xor(p[e], off, 64);
  if (lane == 0) {
    float mx = -1e30f; int am = 0;
#pragma unroll
    for (int e = 0; e < 8; ++e) { p[e] += br[e]; if (p[e] > mx) { mx = p[e]; am = e; } }
    float s = 0.f; float pr[8];
#pragma unroll
    for (int e = 0; e < 8; ++e) { pr[e] = __expf(p[e] - mx); s += pr[e]; }
    float inv = 1.0f / s;
    routes[n] = am;
    rpm_out[n] = pr[am] * inv;
#pragma unroll
    for (int e = 0; e < 8; ++e) atomicAdd(&lprob[e], pr[e] * inv);
  }
  __syncthreads();
  if (threadIdx.x < 8) atomicAdd(&route_prob[threadIdx.x], lprob[threadIdx.x]);
}

// ---------------- routing scan, 3-phase parallel (exact sequential semantics)
__global__ __launch_bounds__(256) void scan_count_kernel(
    const int* __restrict__ routes, int* __restrict__ locpos,
    int* __restrict__ blockcnt) {
  __shared__ int wcnt[4][8];
  int tid = threadIdx.x, lane = tid & 63, w = tid >> 6;
  int n = blockIdx.x * 256 + tid;
  int r = routes[n];
  int p_in_wave = 0;
#pragma unroll
  for (int e = 0; e < 8; ++e) {
    unsigned long long mk = __ballot(r == e);
    if (lane == 0) wcnt[w][e] = __popcll(mk);
    if (r == e) p_in_wave = __popcll(mk & ((1ull << lane) - 1ull));
  }
  __syncthreads();
  int off = 0;
  for (int ww = 0; ww < w; ++ww) off += wcnt[ww][r];
  locpos[n] = off + p_in_wave;
  if (tid < 8)
    blockcnt[blockIdx.x * 8 + tid] =
        wcnt[0][tid] + wcnt[1][tid] + wcnt[2][tid] + wcnt[3][tid];
}

__global__ __launch_bounds__(64) void scan_base_kernel(
    const int* __restrict__ blockcnt, int* __restrict__ blockbase,
    int* __restrict__ cnt_kept, float* __restrict__ counts_out,
    float* __restrict__ ndrop_out) {
  __shared__ int tot[8];
  int e = threadIdx.x;
  if (e < 8) {
    int run = 0;
    for (int b = 0; b < 64; ++b) { blockbase[b * 8 + e] = run; run += blockcnt[b * 8 + e]; }
    counts_out[e] = (float)run;
    cnt_kept[e] = run < CAPE ? run : CAPE;
    tot[e] = run;
  }
  __syncthreads();
  if (e == 0) {
    int nd = 0;
    for (int i = 0; i < 8; ++i) nd += (tot[i] > CAPE) ? (tot[i] - CAPE) : 0;
    ndrop_out[0] = (float)nd;
  }
}

__global__ __launch_bounds__(256) void scan_fill_kernel(
    const int* __restrict__ routes, const int* __restrict__ locpos,
    const int* __restrict__ blockbase, int* __restrict__ pos,
    int* __restrict__ toklist) {
  int n = blockIdx.x * 256 + threadIdx.x;
  int r = routes[n];
  int pn = blockbase[blockIdx.x * 8 + r] + locpos[n];
  pos[n] = pn;
  if (pn < CAPE) toklist[r * CAPE + pn] = n;
}

// ---------------- transpose + fp32->bf16 convert: out[C][R] = bf16(in[R][C]), per expert z
__global__ __launch_bounds__(256) void transpose_bf16_kernel(
    const float* __restrict__ in, ushort* __restrict__ out, int R, int C) {
  __shared__ float T[64][65];
  int e = blockIdx.z;
  const float* src = in + (size_t)e * R * C;
  ushort* dst = out + (size_t)e * R * C;
  int c0 = blockIdx.x * 64, r0 = blockIdx.y * 64;
  int tid = threadIdx.x;
#pragma unroll
  for (int i = 0; i < 4; ++i) {
    int idx = tid + i * 256;
    int r = idx >> 4, c4 = (idx & 15) * 4;
    float4 t = *reinterpret_cast<const float4*>(&src[(size_t)(r0 + r) * C + c0 + c4]);
    T[r][c4] = t.x; T[r][c4 + 1] = t.y; T[r][c4 + 2] = t.z; T[r][c4 + 3] = t.w;
  }
  __syncthreads();
  int n = tid >> 2, kg = (tid & 3) * 16;
  uint4 o[2];
  uint* ow = reinterpret_cast<uint*>(o);
#pragma unroll
  for (int wdx = 0; wdx < 8; ++wdx)
    ow[wdx] = (unsigned)f2bf(T[kg + 2 * wdx][n]) | ((unsigned)f2bf(T[kg + 2 * wdx + 1][n]) << 16);
  *reinterpret_cast<uint4*>(&dst[(size_t)(c0 + n) * R + r0 + kg]) = o[0];
  *reinterpret_cast<uint4*>(&dst[(size_t)(c0 + n) * R + r0 + kg + 8]) = o[1];
}

// ---------------- MoE GEMM1: 256x128 tile, 8 waves, XCD swizzle
__global__ __launch_bounds__(512) void moe_gemm1_kernel(
    const ushort* __restrict__ x1bf, const ushort* __restrict__ W1t,
    const float* __restrict__ b1, const int* __restrict__ toklist,
    const int* __restrict__ cnt_kept, ushort* __restrict__ H, int f0base) {
  __shared__ __align__(16) ushort As[256][64];
  __shared__ __align__(16) ushort Bs[128][64];
  __shared__ int toks[256];
  int nwg = gridDim.x * gridDim.y * gridDim.z;
  int linear = blockIdx.x + gridDim.x * (blockIdx.y + gridDim.y * blockIdx.z);
  int swz = (linear % 8) * (nwg / 8) + linear / 8;
  int bx = swz % gridDim.x;
  int tmp = swz / gridDim.x;
  int by = tmp % gridDim.y;
  int e = tmp / gridDim.y;
  int cnt = cnt_kept[e];
  int m0 = by * 256;
  if (m0 >= cnt) return;
  int n0 = bx * 128;
  int tid = threadIdx.x;
  int wave = tid >> 6, lane = tid & 63;
  int wm = wave >> 1, wn = wave & 1;
  int c16 = lane & 15, g = lane >> 4;

  for (int i = tid; i < 256; i += 512) {
    int idx = m0 + i;
    toks[i] = toklist[e * CAPE + (idx < cnt ? idx : 0)];
  }
  __syncthreads();

  int row_in = lane >> 3, k8 = (lane & 7) * 8;
  size_t atok[4];
#pragma unroll
  for (int i = 0; i < 4; ++i)
    atok[i] = (size_t)toks[wave * 32 + i * 8 + row_in] * DMODEL;
  const ushort* Wbase = W1t + ((size_t)e * DFF + f0base + n0) * DMODEL;
  f32x4 acc[4][4] = {};

  for (int k0 = 0; k0 < DMODEL; k0 += 64) {
#pragma unroll
    for (int i = 0; i < 4; ++i) {
      int rowa = wave * 32 + i * 8;
      gload_lds16(x1bf + atok[i] + k0 + k8, &As[rowa][0]);
    }
#pragma unroll
    for (int i = 0; i < 2; ++i) {
      int rowb = wave * 16 + i * 8;
      gload_lds16(Wbase + (size_t)(rowb + row_in) * DMODEL + k0 + k8, &Bs[rowb][0]);
    }
    __syncthreads();
#pragma unroll
    for (int ks = 0; ks < 2; ++ks) {
      bf16x8 af[4], bfr[4];
#pragma unroll
      for (int mt = 0; mt < 4; ++mt)
        af[mt] = *reinterpret_cast<bf16x8*>(&As[wm * 64 + mt * 16 + c16][ks * 32 + g * 8]);
#pragma unroll
      for (int nt = 0; nt < 4; ++nt)
        bfr[nt] = *reinterpret_cast<bf16x8*>(&Bs[wn * 64 + nt * 16 + c16][ks * 32 + g * 8]);
#pragma unroll
      for (int mt = 0; mt < 4; ++mt)
#pragma unroll
        for (int nt = 0; nt < 4; ++nt)
          acc[mt][nt] = __builtin_amdgcn_mfma_f32_16x16x32_bf16(af[mt], bfr[nt], acc[mt][nt], 0, 0, 0);
    }
    __syncthreads();
  }
  int rowq = g * 4;
#pragma unroll
  for (int mt = 0; mt < 4; ++mt) {
#pragma unroll
    for (int i = 0; i < 4; ++i) {
      int mm = wm * 64 + mt * 16 + rowq + i;
      if (m0 + mm < cnt) {
        size_t hb = (size_t)toks[mm] * 1024;
#pragma unroll
        for (int nt = 0; nt < 4; ++nt) {
          int col = n0 + wn * 64 + nt * 16 + c16;
          float v = acc[mt][nt][i] + b1[e * DFF + f0base + col];
          H[hb + col] = f2bf(fmaxf(v, 0.f));
        }
      }
    }
  }
}

// ---------------- MoE GEMM2: 256x128 tile, 8 waves, XCD swizzle (bf16 ybuf)
__global__ __launch_bounds__(512) void moe_gemm2_kernel(
    const ushort* __restrict__ H, const ushort* __restrict__ W2t,
    const float* __restrict__ b2, const int* __restrict__ toklist,
    const int* __restrict__ cnt_kept, ushort* __restrict__ ybuf,
    int f0base, int addprev) {
  __shared__ __align__(16) ushort As[256][64];
  __shared__ __align__(16) ushort Bs[128][64];
  __shared__ int toks[256];
  int nwg = gridDim.x * gridDim.y * gridDim.z;
  int linear = blockIdx.x + gridDim.x * (blockIdx.y + gridDim.y * blockIdx.z);
  int swz = (linear % 8) * (nwg / 8) + linear / 8;
  int bx = swz % gridDim.x;
  int tmp = swz / gridDim.x;
  int by = tmp % gridDim.y;
  int e = tmp / gridDim.y;
  int cnt = cnt_kept[e];
  int m0 = by * 256;
  if (m0 >= cnt) return;
  int n0 = bx * 128;
  int tid = threadIdx.x;
  int wave = tid >> 6, lane = tid & 63;
  int wm = wave >> 1, wn = wave & 1;
  int c16 = lane & 15, g = lane >> 4;

  for (int i = tid; i < 256; i += 512) {
    int idx = m0 + i;
    toks[i] = toklist[e * CAPE + (idx < cnt ? idx : 0)];
  }
  __syncthreads();

  int row_in = lane >> 3, k8 = (lane & 7) * 8;
  size_t atok[4];
#pragma unroll
  for (int i = 0; i < 4; ++i)
    atok[i] = (size_t)toks[wave * 32 + i * 8 + row_in] * 1024;
  const ushort* Wbase = W2t + ((size_t)e * DMODEL + n0) * DFF + f0base;
  f32x4 acc[4][4] = {};

  for (int k0 = 0; k0 < 1024; k0 += 64) {
#pragma unroll
    for (int i = 0; i < 4; ++i) {
      int rowa = wave * 32 + i * 8;
      gload_lds16(H + atok[i] + k0 + k8, &As[rowa][0]);
    }
#pragma unroll
    for (int i = 0; i < 2; ++i) {
      int rowb = wave * 16 + i * 8;
      gload_lds16(Wbase + (size_t)(rowb + row_in) * DFF + k0 + k8, &Bs[rowb][0]);
    }
    __syncthreads();
#pragma unroll
    for (int ks = 0; ks < 2; ++ks) {
      bf16x8 af[4], bfr[4];
#pragma unroll
      for (int mt = 0; mt < 4; ++mt)
        af[mt] = *reinterpret_cast<bf16x8*>(&As[wm * 64 + mt * 16 + c16][ks * 32 + g * 8]);
#pragma unroll
      for (int nt = 0; nt < 4; ++nt)
        bfr[nt] = *reinterpret_cast<bf16x8*>(&Bs[wn * 64 + nt * 16 + c16][ks * 32 + g * 8]);
#pragma unroll
      for (int mt = 0; mt < 4; ++mt)
#pragma unroll
        for (int nt = 0; nt < 4; ++nt)
          acc[mt][nt] = __builtin_amdgcn_mfma_f32_16x16x32_bf16(af[mt], bfr[nt], acc[mt][nt], 0, 0, 0);
    }
    __syncthreads();
  }
  int rowq = g * 4;
#pragma unroll
  for (int mt = 0; mt < 4; ++mt) {
#pragma unroll
    for (int i = 0; i < 4; ++i) {
      int mm = wm * 64 + mt * 16 + rowq + i;
      if (m0 + mm < cnt) {
        size_t yb = (size_t)toks[mm] * DMODEL;
#pragma unroll
        for (int nt = 0; nt < 4; ++nt) {
          int col = n0 + wn * 64 + nt * 16 + c16;
          float v = acc[mt][nt][i];
          v += addprev ? bf2f(ybuf[yb + col]) : b2[e * DMODEL + col];
          ybuf[yb + col] = f2bf(v);
        }
      }
    }
  }
}

// ---------------- combine + final LayerNorm (ybuf bf16)
__global__ __launch_bounds__(256) void final_ln_kernel(
    const float* __restrict__ x1, const ushort* __restrict__ ybuf,
    const int* __restrict__ pos, const float* __restrict__ rpm,
    const float* __restrict__ g, const float* __restrict__ beta,
    float* __restrict__ out) {
  __shared__ float red[4];
  int row = blockIdx.x, tid = threadIdx.x;
  size_t base = (size_t)row * DMODEL;
  bool kept = pos[row] < CAPE;
  float scale = rpm[row];
  float a0 = x1[base + tid], a1 = x1[base + tid + 256];
  float y0 = (kept ? bf2f(ybuf[base + tid])       : a0) * scale;
  float y1 = (kept ? bf2f(ybuf[base + tid + 256]) : a1) * scale;
  float v0 = a0 + y0, v1 = a1 + y1;
  float s = block_reduce_sum(v0 + v1, red);
  float mean = s * (1.0f / DMODEL);
  float d0 = v0 - mean, d1 = v1 - mean;
  float vs = block_reduce_sum(d0 * d0 + d1 * d1, red);
  float inv = rsqrtf(vs * (1.0f / DMODEL) + LNEPS);
  out[base + tid]       = d0 * inv * g[tid] + beta[tid];
  out[base + tid + 256] = d1 * inv * g[tid + 256] + beta[tid + 256];
}

__global__ void zero_small_kernel(float* route_prob) {
  if (threadIdx.x < 8) route_prob[threadIdx.x] = 0.f;
}

extern "C" void kernel_launch(void* const* d_in, const int* in_sizes, int n_in,
                              void* d_out, int out_size, void* d_ws, size_t ws_size,
                              hipStream_t stream) {
  const float* x    = (const float*)d_in[0];
  const float* Wq   = (const float*)d_in[1];
  const float* bq   = (const float*)d_in[2];
  const float* Wk   = (const float*)d_in[3];
  const float* bk   = (const float*)d_in[4];
  const float* Wv   = (const float*)d_in[5];
  const float* bv   = (const float*)d_in[6];
  const float* Wo   = (const float*)d_in[7];
  const float* bo   = (const float*)d_in[8];
  const float* ln1g = (const float*)d_in[9];
  const float* ln1b = (const float*)d_in[10];
  const float* Wr   = (const float*)d_in[11];
  const float* br   = (const float*)d_in[12];
  const float* W1   = (const float*)d_in[13];
  const float* b1   = (const float*)d_in[14];
  const float* W2   = (const float*)d_in[15];
  const float* b2   = (const float*)d_in[16];
  const float* ln2g = (const float*)d_in[17];
  const float* ln2b = (const float*)d_in[18];

  float* ws = (float*)d_ws;
  const size_t ND = (size_t)NTOK * DMODEL;
  float* qb   = ws;
  float* kb   = ws + ND;
  float* vb   = ws + 2 * ND;
  float* out  = (float*)d_out;
  float* ctxb = out;            // d_out region as ctx scratch (pre-MoE)
  float* tmpb = qb;             // O-proj output (q consumed by attention)
  float* x1b  = vb;             // post-LN1 fp32 (v consumed by attention)
  ushort* ybuf  = (ushort*)kb;            // FFN output, bf16
  ushort* x1bfb = (ushort*)kb + ND;       // bf16 x1
  ushort* Hbuf = (ushort*)qb;   // half-F H buffer
  ushort* W1th = (ushort*)out;
  ushort* W2th = W1th + (size_t)NEXP * DFF * DMODEL;
  const size_t WSZ = (size_t)3 * DMODEL * DMODEL;
  ushort* Wq3 = (ushort*)out;
  ushort* Wk3 = Wq3 + WSZ;
  ushort* Wv3 = Wk3 + WSZ;
  ushort* Wo3 = (ushort*)kb;
  int* routes   = (int*)(ws + 3 * ND);
  int* posb     = routes + NTOK;
  int* toklist  = posb + NTOK;
  int* cnt_kept = toklist + NEXP * CAPE;
  int* locpos    = (int*)qb;
  int* blockcnt  = locpos + NTOK;
  int* blockbase = blockcnt + 512;

  float* counts_out = out + ND;
  float* rp_out     = counts_out + 8;
  float* nd_out     = rp_out + 8;
  float* rpm_out    = nd_out + 1;

  zero_small_kernel<<<1, 64, 0, stream>>>(rp_out);

  dim3 wg(8, 8);
  wsplit3_kernel<<<wg, 256, 0, stream>>>(Wq, Wq3, DMODEL, DMODEL);
  wsplit3_kernel<<<wg, 256, 0, stream>>>(Wk, Wk3, DMODEL, DMODEL);
  wsplit3_kernel<<<wg, 256, 0, stream>>>(Wv, Wv3, DMODEL, DMODEL);

  dim3 gg(DMODEL / 128, NTOK / 256);
  gemm_split3_kernel<<<gg, 512, 0, stream>>>(x, Wq3, bq, qb, NTOK, DMODEL, DMODEL);
  gemm_split3_kernel<<<gg, 512, 0, stream>>>(x, Wk3, bk, kb, NTOK, DMODEL, DMODEL);
  gemm_split3_kernel<<<gg, 512, 0, stream>>>(x, Wv3, bv, vb, NTOK, DMODEL, DMODEL);

  attn_kernel<<<BATCH * NHEAD * (SEQ / 256), 512, 0, stream>>>(qb, kb, vb, ctxb);

  wsplit3_kernel<<<wg, 256, 0, stream>>>(Wo, Wo3, DMODEL, DMODEL);
  gemm_split3_kernel<<<gg, 512, 0, stream>>>(ctxb, Wo3, bo, tmpb, NTOK, DMODEL, DMODEL);
  add_ln_kernel<<<NTOK, 256, 0, stream>>>(x, tmpb, ln1g, ln1b, x1b, x1bfb);

  transpose_bf16_kernel<<<dim3(DFF / 64, DMODEL / 64, NEXP), 256, 0, stream>>>(
      W1, W1th, DMODEL, DFF);
  transpose_bf16_kernel<<<dim3(DMODEL / 64, DFF / 64, NEXP), 256, 0, stream>>>(
      W2, W2th, DFF, DMODEL);

  router_kernel<<<NTOK / 4, 256, 0, stream>>>(x1b, Wr, br, routes, rpm_out, rp_out);
  scan_count_kernel<<<64, 256, 0, stream>>>(routes, locpos, blockcnt);
  scan_base_kernel<<<1, 64, 0, stream>>>(blockcnt, blockbase, cnt_kept, counts_out, nd_out);
  scan_fill_kernel<<<64, 256, 0, stream>>>(routes, locpos, blockbase, posb, toklist);

  dim3 g1(8, CAPE / 256, NEXP);
  dim3 g2(4, CAPE / 256, NEXP);
  moe_gemm1_kernel<<<g1, 512, 0, stream>>>(x1bfb, W1th, b1, toklist, cnt_kept, Hbuf, 0);
  moe_gemm2_kernel<<<g2, 512, 0, stream>>>(Hbuf, W2th, b2, toklist, cnt_kept, ybuf, 0, 0);
  moe_gemm1_kernel<<<g1, 512, 0, stream>>>(x1bfb, W1th, b1, toklist, cnt_kept, Hbuf, 1024);
  moe_gemm2_kernel<<<g2, 512, 0, stream>>>(Hbuf, W2th, b2, toklist, cnt_kept, ybuf, 1024, 1);

  final_ln_kernel<<<NTOK, 256, 0, stream>>>(x1b, ybuf, posb, rpm_out, ln2g, ln2b, out);
}

// Round 19
// 719.642 us; speedup vs baseline: 1.0197x; 1.0197x over previous
//
#include <hip/hip_runtime.h>
#include <hip/hip_bf16.h>
#include <math.h>

#define NTOK   16384
#define DMODEL 512
#define NHEAD  8
#define DHEAD  64
#define NEXP   8
#define DFF    2048
#define SEQ    1024
#define BATCH  16
#define CAPE   2560
#define LNEPS  1e-5f

typedef __attribute__((ext_vector_type(8))) short bf16x8;
typedef __attribute__((ext_vector_type(4))) float f32x4;

__device__ inline ushort f2bf(float f) {
  union { float f; unsigned int u; } v; v.f = f;
  unsigned int u = v.u + 0x7fffu + ((v.u >> 16) & 1u);
  return (ushort)(u >> 16);
}
__device__ inline float bf2f(ushort h) {
  union { unsigned int u; float f; } v; v.u = ((unsigned)h) << 16; return v.f;
}
__device__ inline unsigned fbits(float x) { union { float f; unsigned u; } v; v.f = x; return v.u; }
__device__ inline float fval(unsigned u) { union { unsigned u; float f; } v; v.u = u; return v.f; }
// truncation 3-split: x == hi16(u0) + hi16(u1) + hi16(u2) (as bf16 planes), error ~2^-22|x|
__device__ __forceinline__ void tsplit3(float x, unsigned& u0, unsigned& u1, unsigned& u2) {
  u0 = fbits(x);
  float r1 = x - fval(u0 & 0xFFFF0000u);
  u1 = fbits(r1);
  float r2 = r1 - fval(u1 & 0xFFFF0000u);
  u2 = fbits(r2);
}
__device__ __forceinline__ unsigned packhi(unsigned lo, unsigned hi) {
  return (hi & 0xFFFF0000u) | (lo >> 16);
}
// async global->LDS, 16B per lane; lds base must be wave-uniform
__device__ __forceinline__ void gload_lds16(const void* g, void* l) {
  __builtin_amdgcn_global_load_lds(
      (const __attribute__((address_space(1))) unsigned int*)g,
      (__attribute__((address_space(3))) unsigned int*)l, 16, 0, 0);
}

// ---------------- W pre-split: in W[R=K][C=N] fp32 -> out[3][N][K] bf16 planes
__global__ __launch_bounds__(256) void wsplit3_kernel(
    const float* __restrict__ in, ushort* __restrict__ out, int R, int C) {
  __shared__ float T[64][65];
  int c0 = blockIdx.x * 64, r0 = blockIdx.y * 64;
  int tid = threadIdx.x;
  size_t plane = (size_t)R * C;
#pragma unroll
  for (int i = 0; i < 4; ++i) {
    int idx = tid + i * 256;
    int r = idx >> 4, c4 = (idx & 15) * 4;
    float4 t = *reinterpret_cast<const float4*>(&in[(size_t)(r0 + r) * C + c0 + c4]);
    T[r][c4] = t.x; T[r][c4 + 1] = t.y; T[r][c4 + 2] = t.z; T[r][c4 + 3] = t.w;
  }
  __syncthreads();
  int n = tid >> 2, kg = (tid & 3) * 16;
  ushort p0[16], p1[16], p2[16];
#pragma unroll
  for (int j = 0; j < 16; ++j) {
    unsigned u0, u1, u2;
    tsplit3(T[kg + j][n], u0, u1, u2);
    p0[j] = (ushort)(u0 >> 16);
    p1[j] = (ushort)(u1 >> 16);
    p2[j] = (ushort)(u2 >> 16);
  }
  size_t ob = (size_t)(c0 + n) * R + r0 + kg;
  *reinterpret_cast<uint4*>(&out[ob])                  = *reinterpret_cast<uint4*>(&p0[0]);
  *reinterpret_cast<uint4*>(&out[ob + 8])              = *reinterpret_cast<uint4*>(&p0[8]);
  *reinterpret_cast<uint4*>(&out[plane + ob])          = *reinterpret_cast<uint4*>(&p1[0]);
  *reinterpret_cast<uint4*>(&out[plane + ob + 8])      = *reinterpret_cast<uint4*>(&p1[8]);
  *reinterpret_cast<uint4*>(&out[2 * plane + ob])      = *reinterpret_cast<uint4*>(&p2[0]);
  *reinterpret_cast<uint4*>(&out[2 * plane + ob + 8])  = *reinterpret_cast<uint4*>(&p2[8]);
}

// ---------------- fp32-equivalent proj GEMM via 6-term split-3 bf16 MFMA.
// 128x128 tile, BK=32, 4 waves (2x2). LDS seg-XOR swizzle on both operands.
__global__ __launch_bounds__(256) void gemm_split3_kernel(
    const float* __restrict__ A, const ushort* __restrict__ W3,
    const float* __restrict__ bias, float* __restrict__ Co,
    int M, int K, int N) {
  __shared__ __align__(16) ushort As3[3][128][32];
  __shared__ __align__(16) ushort Bs3[3][128][32];
  int tid = threadIdx.x;
  int wave = tid >> 6, lane = tid & 63;
  int wm = wave >> 1, wn = wave & 1;
  int c16 = lane & 15, g = lane >> 4;
  int row0 = blockIdx.y * 128, col0 = blockIdx.x * 128;
  size_t plane = (size_t)K * N;
  int ar = tid >> 1, ah = tid & 1;
  int rloc = lane >> 2;
  int bseg = ((lane & 3) ^ (rloc & 3)) * 8;
  int q0s = (ah * 2) ^ (ar & 3);
  int q1s = (ah * 2 + 1) ^ (ar & 3);
  int ksw = (g ^ (c16 & 3)) * 8;
  f32x4 acc[4][4] = {};

  for (int k0 = 0; k0 < K; k0 += 32) {
#pragma unroll
    for (int ch = 0; ch < 6; ++ch) {
      int s = ch >> 1, h = ch & 1;
      int rowb = h * 64 + wave * 16;
      gload_lds16(W3 + (size_t)s * plane + (size_t)(col0 + rowb + rloc) * K + k0 + bseg,
                  &Bs3[s][rowb][0]);
    }
    {
      const float* ap = A + (size_t)(row0 + ar) * K + k0 + ah * 16;
      float xs[16];
#pragma unroll
      for (int i = 0; i < 4; ++i) {
        float4 t = *reinterpret_cast<const float4*>(ap + i * 4);
        xs[i * 4] = t.x; xs[i * 4 + 1] = t.y; xs[i * 4 + 2] = t.z; xs[i * 4 + 3] = t.w;
      }
      ushort p0[16], p1[16], p2[16];
#pragma unroll
      for (int j = 0; j < 16; ++j) {
        unsigned u0, u1, u2;
        tsplit3(xs[j], u0, u1, u2);
        p0[j] = (ushort)(u0 >> 16);
        p1[j] = (ushort)(u1 >> 16);
        p2[j] = (ushort)(u2 >> 16);
      }
      *reinterpret_cast<uint4*>(&As3[0][ar][q0s * 8]) = *reinterpret_cast<uint4*>(&p0[0]);
      *reinterpret_cast<uint4*>(&As3[0][ar][q1s * 8]) = *reinterpret_cast<uint4*>(&p0[8]);
      *reinterpret_cast<uint4*>(&As3[1][ar][q0s * 8]) = *reinterpret_cast<uint4*>(&p1[0]);
      *reinterpret_cast<uint4*>(&As3[1][ar][q1s * 8]) = *reinterpret_cast<uint4*>(&p1[8]);
      *reinterpret_cast<uint4*>(&As3[2][ar][q0s * 8]) = *reinterpret_cast<uint4*>(&p2[0]);
      *reinterpret_cast<uint4*>(&As3[2][ar][q1s * 8]) = *reinterpret_cast<uint4*>(&p2[8]);
    }
    __syncthreads();
    bf16x8 bfr[4][3];
#pragma unroll
    for (int nt = 0; nt < 4; ++nt)
#pragma unroll
      for (int s = 0; s < 3; ++s)
        bfr[nt][s] = *reinterpret_cast<bf16x8*>(&Bs3[s][wn * 64 + nt * 16 + c16][ksw]);
#pragma unroll
    for (int mt = 0; mt < 4; ++mt) {
      int arow = wm * 64 + mt * 16 + c16;
      bf16x8 a0 = *reinterpret_cast<bf16x8*>(&As3[0][arow][ksw]);
      bf16x8 a1 = *reinterpret_cast<bf16x8*>(&As3[1][arow][ksw]);
      bf16x8 a2 = *reinterpret_cast<bf16x8*>(&As3[2][arow][ksw]);
#pragma unroll
      for (int nt = 0; nt < 4; ++nt) {
        acc[mt][nt] = __builtin_amdgcn_mfma_f32_16x16x32_bf16(a0, bfr[nt][0], acc[mt][nt], 0, 0, 0);
        acc[mt][nt] = __builtin_amdgcn_mfma_f32_16x16x32_bf16(a0, bfr[nt][1], acc[mt][nt], 0, 0, 0);
        acc[mt][nt] = __builtin_amdgcn_mfma_f32_16x16x32_bf16(a1, bfr[nt][0], acc[mt][nt], 0, 0, 0);
        acc[mt][nt] = __builtin_amdgcn_mfma_f32_16x16x32_bf16(a1, bfr[nt][1], acc[mt][nt], 0, 0, 0);
        acc[mt][nt] = __builtin_amdgcn_mfma_f32_16x16x32_bf16(a0, bfr[nt][2], acc[mt][nt], 0, 0, 0);
        acc[mt][nt] = __builtin_amdgcn_mfma_f32_16x16x32_bf16(a2, bfr[nt][0], acc[mt][nt], 0, 0, 0);
      }
    }
    __syncthreads();
  }
  int rowq = g * 4;
#pragma unroll
  for (int mt = 0; mt < 4; ++mt) {
#pragma unroll
    for (int i = 0; i < 4; ++i) {
      int r = row0 + wm * 64 + mt * 16 + rowq + i;
#pragma unroll
      for (int nt = 0; nt < 4; ++nt) {
        int c = col0 + wn * 64 + nt * 16 + c16;
        Co[(size_t)r * N + c] = acc[mt][nt][i] + bias[c];
      }
    }
  }
}

// ---------------- flash attention, fp32-equivalent via trunc-split bf16 MFMA.
// 512 threads = 8 waves; q-tile 256 rows as TWO 128-row halves sharing staged K/V
// AND sharing kf/vf fragment loads (pfA captured in regs before Ps reuse).
#define KC 32
__global__ __launch_bounds__(512, 4) void attn_kernel(
    const float* __restrict__ q, const float* __restrict__ k,
    const float* __restrict__ v, float* __restrict__ ctx) {
  __shared__ short Ks[3][KC][72];    // [split][key][dim]
  __shared__ short Vt[3][64][40];    // [split][dim][key]
  __shared__ short Ps[3][128][40];   // [split][qrow(half)][key] — reused A then B
  int tid = threadIdx.x;
  int w = tid >> 6, lane = tid & 63;
  int g = lane >> 4, c16 = lane & 15;
  int bid = blockIdx.x;
  int qt = bid & 3, h = (bid >> 2) & 7, b = bid >> 5;
  int q0 = qt * 256;
  size_t basebh = (size_t)b * SEQ * DMODEL + (size_t)h * DHEAD;

  // ---- Q fragments for both halves (scaled 1/8), trunc-split
  bf16x8 qfA[2][3], qfB[2][3];
  {
    int qrowA = q0 + w * 16 + c16;
    int qrowB = qrowA + 128;
    const float* qpA = &q[basebh + (size_t)qrowA * DMODEL];
    const float* qpB = &q[basebh + (size_t)qrowB * DMODEL];
#pragma unroll
    for (int ks = 0; ks < 2; ++ks) {
      int d0 = ks * 32 + g * 8;
      float4 fa = *reinterpret_cast<const float4*>(qpA + d0);
      float4 fb = *reinterpret_cast<const float4*>(qpA + d0 + 4);
      float xs[8] = {fa.x, fa.y, fa.z, fa.w, fb.x, fb.y, fb.z, fb.w};
#pragma unroll
      for (int j = 0; j < 8; ++j) {
        unsigned u0, u1, u2;
        tsplit3(xs[j] * 0.125f, u0, u1, u2);
        qfA[ks][0][j] = (short)(u0 >> 16);
        qfA[ks][1][j] = (short)(u1 >> 16);
        qfA[ks][2][j] = (short)(u2 >> 16);
      }
      float4 fc = *reinterpret_cast<const float4*>(qpB + d0);
      float4 fd = *reinterpret_cast<const float4*>(qpB + d0 + 4);
      float ys[8] = {fc.x, fc.y, fc.z, fc.w, fd.x, fd.y, fd.z, fd.w};
#pragma unroll
      for (int j = 0; j < 8; ++j) {
        unsigned u0, u1, u2;
        tsplit3(ys[j] * 0.125f, u0, u1, u2);
        qfB[ks][0][j] = (short)(u0 >> 16);
        qfB[ks][1][j] = (short)(u1 >> 16);
        qfB[ks][2][j] = (short)(u2 >> 16);
      }
    }
  }

  f32x4 OA[4] = {}, OB[4] = {};
  float lrowA[4] = {}, lrowB[4] = {};

  int skey = tid >> 4, sd0 = (tid & 15) * 4;        // K: key, 4 dims
  int vd2 = (tid & 31) * 2, kp2 = (tid >> 5) * 2;   // V: 2 dims x 2 keys

  for (int kc = 0; kc < SEQ; kc += KC) {
    // ---- stage K chunk (4 elems/thread), trunc-split, uint2 writes
    {
      const float* kp = &k[basebh + (size_t)(kc + skey) * DMODEL + sd0];
      float4 fa = *reinterpret_cast<const float4*>(kp);
      float xs[4] = {fa.x, fa.y, fa.z, fa.w};
      unsigned u[3][4];
#pragma unroll
      for (int j = 0; j < 4; ++j) tsplit3(xs[j], u[0][j], u[1][j], u[2][j]);
#pragma unroll
      for (int s = 0; s < 3; ++s) {
        uint2 pk;
        pk.x = packhi(u[s][0], u[s][1]);
        pk.y = packhi(u[s][2], u[s][3]);
        *reinterpret_cast<uint2*>(&Ks[s][skey][sd0]) = pk;
      }
    }
    // ---- stage V chunk transposed (4 elems/thread)
    {
      const float* vpa = &v[basebh + (size_t)(kc + kp2) * DMODEL + vd2];
      float2 va = *reinterpret_cast<const float2*>(vpa);
      float2 vb2 = *reinterpret_cast<const float2*>(vpa + DMODEL);
      unsigned a0, a1, a2, b0, b1, b2;
      tsplit3(va.x, a0, a1, a2);
      tsplit3(vb2.x, b0, b1, b2);
      *reinterpret_cast<unsigned*>(&Vt[0][vd2][kp2]) = packhi(a0, b0);
      *reinterpret_cast<unsigned*>(&Vt[1][vd2][kp2]) = packhi(a1, b1);
      *reinterpret_cast<unsigned*>(&Vt[2][vd2][kp2]) = packhi(a2, b2);
      tsplit3(va.y, a0, a1, a2);
      tsplit3(vb2.y, b0, b1, b2);
      *reinterpret_cast<unsigned*>(&Vt[0][vd2 + 1][kp2]) = packhi(a0, b0);
      *reinterpret_cast<unsigned*>(&Vt[1][vd2 + 1][kp2]) = packhi(a1, b1);
      *reinterpret_cast<unsigned*>(&Vt[2][vd2 + 1][kp2]) = packhi(a2, b2);
    }
    __syncthreads();

    // ---- merged QK^T: one kf load feeds both halves
    f32x4 SA[2] = {}, SB[2] = {};
#pragma unroll
    for (int ks = 0; ks < 2; ++ks) {
      bf16x8 kf[2][3];
#pragma unroll
      for (int nt = 0; nt < 2; ++nt)
#pragma unroll
        for (int s = 0; s < 3; ++s)
          kf[nt][s] = *reinterpret_cast<bf16x8*>(&Ks[s][nt * 16 + c16][ks * 32 + g * 8]);
#pragma unroll
      for (int nt = 0; nt < 2; ++nt) {
        SA[nt] = __builtin_amdgcn_mfma_f32_16x16x32_bf16(qfA[ks][0], kf[nt][0], SA[nt], 0, 0, 0);
        SA[nt] = __builtin_amdgcn_mfma_f32_16x16x32_bf16(qfA[ks][0], kf[nt][1], SA[nt], 0, 0, 0);
        SA[nt] = __builtin_amdgcn_mfma_f32_16x16x32_bf16(qfA[ks][1], kf[nt][0], SA[nt], 0, 0, 0);
        SA[nt] = __builtin_amdgcn_mfma_f32_16x16x32_bf16(qfA[ks][1], kf[nt][1], SA[nt], 0, 0, 0);
        SA[nt] = __builtin_amdgcn_mfma_f32_16x16x32_bf16(qfA[ks][0], kf[nt][2], SA[nt], 0, 0, 0);
        SA[nt] = __builtin_amdgcn_mfma_f32_16x16x32_bf16(qfA[ks][2], kf[nt][0], SA[nt], 0, 0, 0);
        SB[nt] = __builtin_amdgcn_mfma_f32_16x16x32_bf16(qfB[ks][0], kf[nt][0], SB[nt], 0, 0, 0);
        SB[nt] = __builtin_amdgcn_mfma_f32_16x16x32_bf16(qfB[ks][0], kf[nt][1], SB[nt], 0, 0, 0);
        SB[nt] = __builtin_amdgcn_mfma_f32_16x16x32_bf16(qfB[ks][1], kf[nt][0], SB[nt], 0, 0, 0);
        SB[nt] = __builtin_amdgcn_mfma_f32_16x16x32_bf16(qfB[ks][1], kf[nt][1], SB[nt], 0, 0, 0);
        SB[nt] = __builtin_amdgcn_mfma_f32_16x16x32_bf16(qfB[ks][0], kf[nt][2], SB[nt], 0, 0, 0);
        SB[nt] = __builtin_amdgcn_mfma_f32_16x16x32_bf16(qfB[ks][2], kf[nt][0], SB[nt], 0, 0, 0);
      }
    }

    // ---- softmax A + Ps store, capture pfA in regs
#pragma unroll
    for (int i = 0; i < 4; ++i) {
      float p0 = __expf(SA[0][i]);
      float p1 = __expf(SA[1][i]);
      lrowA[i] += p0 + p1;
      int prow = w * 16 + g * 4 + i;
      unsigned u0, u1, u2;
      tsplit3(p0, u0, u1, u2);
      Ps[0][prow][c16] = (short)(u0 >> 16);
      Ps[1][prow][c16] = (short)(u1 >> 16);
      Ps[2][prow][c16] = (short)(u2 >> 16);
      tsplit3(p1, u0, u1, u2);
      Ps[0][prow][c16 + 16] = (short)(u0 >> 16);
      Ps[1][prow][c16 + 16] = (short)(u1 >> 16);
      Ps[2][prow][c16 + 16] = (short)(u2 >> 16);
    }
    bf16x8 pfA0 = *reinterpret_cast<bf16x8*>(&Ps[0][w * 16 + c16][g * 8]);
    bf16x8 pfA1 = *reinterpret_cast<bf16x8*>(&Ps[1][w * 16 + c16][g * 8]);
    bf16x8 pfA2 = *reinterpret_cast<bf16x8*>(&Ps[2][w * 16 + c16][g * 8]);

    // ---- softmax B overwrites wave-private Ps rows (in-order DS pipe), capture pfB
#pragma unroll
    for (int i = 0; i < 4; ++i) {
      float p0 = __expf(SB[0][i]);
      float p1 = __expf(SB[1][i]);
      lrowB[i] += p0 + p1;
      int prow = w * 16 + g * 4 + i;
      unsigned u0, u1, u2;
      tsplit3(p0, u0, u1, u2);
      Ps[0][prow][c16] = (short)(u0 >> 16);
      Ps[1][prow][c16] = (short)(u1 >> 16);
      Ps[2][prow][c16] = (short)(u2 >> 16);
      tsplit3(p1, u0, u1, u2);
      Ps[0][prow][c16 + 16] = (short)(u0 >> 16);
      Ps[1][prow][c16 + 16] = (short)(u1 >> 16);
      Ps[2][prow][c16 + 16] = (short)(u2 >> 16);
    }
    bf16x8 pfB0 = *reinterpret_cast<bf16x8*>(&Ps[0][w * 16 + c16][g * 8]);
    bf16x8 pfB1 = *reinterpret_cast<bf16x8*>(&Ps[1][w * 16 + c16][g * 8]);
    bf16x8 pfB2 = *reinterpret_cast<bf16x8*>(&Ps[2][w * 16 + c16][g * 8]);

    // ---- shared PV: one vf load feeds both halves
#pragma unroll
    for (int dt = 0; dt < 4; ++dt) {
      bf16x8 vf[3];
#pragma unroll
      for (int s = 0; s < 3; ++s)
        vf[s] = *reinterpret_cast<bf16x8*>(&Vt[s][dt * 16 + c16][g * 8]);
      OA[dt] = __builtin_amdgcn_mfma_f32_16x16x32_bf16(pfA0, vf[0], OA[dt], 0, 0, 0);
      OA[dt] = __builtin_amdgcn_mfma_f32_16x16x32_bf16(pfA0, vf[1], OA[dt], 0, 0, 0);
      OA[dt] = __builtin_amdgcn_mfma_f32_16x16x32_bf16(pfA1, vf[0], OA[dt], 0, 0, 0);
      OA[dt] = __builtin_amdgcn_mfma_f32_16x16x32_bf16(pfA1, vf[1], OA[dt], 0, 0, 0);
      OA[dt] = __builtin_amdgcn_mfma_f32_16x16x32_bf16(pfA0, vf[2], OA[dt], 0, 0, 0);
      OA[dt] = __builtin_amdgcn_mfma_f32_16x16x32_bf16(pfA2, vf[0], OA[dt], 0, 0, 0);
      OB[dt] = __builtin_amdgcn_mfma_f32_16x16x32_bf16(pfB0, vf[0], OB[dt], 0, 0, 0);
      OB[dt] = __builtin_amdgcn_mfma_f32_16x16x32_bf16(pfB0, vf[1], OB[dt], 0, 0, 0);
      OB[dt] = __builtin_amdgcn_mfma_f32_16x16x32_bf16(pfB1, vf[0], OB[dt], 0, 0, 0);
      OB[dt] = __builtin_amdgcn_mfma_f32_16x16x32_bf16(pfB1, vf[1], OB[dt], 0, 0, 0);
      OB[dt] = __builtin_amdgcn_mfma_f32_16x16x32_bf16(pfB0, vf[2], OB[dt], 0, 0, 0);
      OB[dt] = __builtin_amdgcn_mfma_f32_16x16x32_bf16(pfB2, vf[0], OB[dt], 0, 0, 0);
    }
    __syncthreads();
  }

  // ---- epilogue: one 16-lane reduction per row per half, then normalize
#pragma unroll
  for (int i = 0; i < 4; ++i) {
    float t = lrowA[i];
#pragma unroll
    for (int off = 1; off < 16; off <<= 1) t += __shfl_xor(t, off, 64);
    float inv = 1.0f / t;
    int qrow = q0 + w * 16 + g * 4 + i;
#pragma unroll
    for (int dt = 0; dt < 4; ++dt)
      ctx[basebh + (size_t)qrow * DMODEL + dt * 16 + c16] = OA[dt][i] * inv;
  }
#pragma unroll
  for (int i = 0; i < 4; ++i) {
    float t = lrowB[i];
#pragma unroll
    for (int off = 1; off < 16; off <<= 1) t += __shfl_xor(t, off, 64);
    float inv = 1.0f / t;
    int qrow = q0 + 128 + w * 16 + g * 4 + i;
#pragma unroll
    for (int dt = 0; dt < 4; ++dt)
      ctx[basebh + (size_t)qrow * DMODEL + dt * 16 + c16] = OB[dt][i] * inv;
  }
}

// ---------------- residual + LayerNorm
__device__ inline float block_reduce_sum(float val, float* red) {
#pragma unroll
  for (int off = 32; off; off >>= 1) val += __shfl_xor(val, off, 64);
  int lane = threadIdx.x & 63, wid = threadIdx.x >> 6;
  __syncthreads();
  if (lane == 0) red[wid] = val;
  __syncthreads();
  return red[0] + red[1] + red[2] + red[3];
}

// add + LN; also emits bf16 copy of the output (for MoE GEMM1 A-operand)
__global__ __launch_bounds__(256) void add_ln_kernel(
    const float* __restrict__ a, const float* __restrict__ bsrc,
    const float* __restrict__ g, const float* __restrict__ beta,
    float* __restrict__ out, ushort* __restrict__ outbf) {
  __shared__ float red[4];
  int row = blockIdx.x, tid = threadIdx.x;
  size_t base = (size_t)row * DMODEL;
  float v0 = a[base + tid] + bsrc[base + tid];
  float v1 = a[base + tid + 256] + bsrc[base + tid + 256];
  float s = block_reduce_sum(v0 + v1, red);
  float mean = s * (1.0f / DMODEL);
  float d0 = v0 - mean, d1 = v1 - mean;
  float vs = block_reduce_sum(d0 * d0 + d1 * d1, red);
  float inv = rsqrtf(vs * (1.0f / DMODEL) + LNEPS);
  float o0 = d0 * inv * g[tid] + beta[tid];
  float o1 = d1 * inv * g[tid + 256] + beta[tid + 256];
  out[base + tid]       = o0;
  out[base + tid + 256] = o1;
  outbf[base + tid]       = f2bf(o0);
  outbf[base + tid + 256] = f2bf(o1);
}

// ---------------- router: 1 wave per token
__global__ __launch_bounds__(256) void router_kernel(
    const float* __restrict__ x1, const float* __restrict__ Wr,
    const float* __restrict__ br, int* __restrict__ routes,
    float* __restrict__ rpm_out, float* __restrict__ route_prob) {
  __shared__ float lprob[8];
  int wid = threadIdx.x >> 6, lane = threadIdx.x & 63;
  int n = blockIdx.x * 4 + wid;
  if (threadIdx.x < 8) lprob[threadIdx.x] = 0.f;
  __syncthreads();
  float p[8] = {};
  size_t base = (size_t)n * DMODEL;
  for (int d = lane; d < DMODEL; d += 64) {
    float xv = x1[base + d];
#pragma unroll
    for (int e = 0; e < 8; ++e) p[e] += xv * Wr[d * 8 + e];
  }
#pragma unroll
  for (int off = 32; off; off >>= 1)
#pragma unroll
    for (int e = 0; e < 8; ++e) p[e] += __shfl_xor(p[e], off, 64);
  if (lane == 0) {
    float mx = -1e30f; int am = 0;
#pragma unroll
    for (int e = 0; e < 8; ++e) { p[e] += br[e]; if (p[e] > mx) { mx = p[e]; am = e; } }
    float s = 0.f; float pr[8];
#pragma unroll
    for (int e = 0; e < 8; ++e) { pr[e] = __expf(p[e] - mx); s += pr[e]; }
    float inv = 1.0f / s;
    routes[n] = am;
    rpm_out[n] = pr[am] * inv;
#pragma unroll
    for (int e = 0; e < 8; ++e) atomicAdd(&lprob[e], pr[e] * inv);
  }
  __syncthreads();
  if (threadIdx.x < 8) atomicAdd(&route_prob[threadIdx.x], lprob[threadIdx.x]);
}

// ---------------- routing scan, 3-phase parallel (exact sequential semantics)
__global__ __launch_bounds__(256) void scan_count_kernel(
    const int* __restrict__ routes, int* __restrict__ locpos,
    int* __restrict__ blockcnt) {
  __shared__ int wcnt[4][8];
  int tid = threadIdx.x, lane = tid & 63, w = tid >> 6;
  int n = blockIdx.x * 256 + tid;
  int r = routes[n];
  int p_in_wave = 0;
#pragma unroll
  for (int e = 0; e < 8; ++e) {
    unsigned long long mk = __ballot(r == e);
    if (lane == 0) wcnt[w][e] = __popcll(mk);
    if (r == e) p_in_wave = __popcll(mk & ((1ull << lane) - 1ull));
  }
  __syncthreads();
  int off = 0;
  for (int ww = 0; ww < w; ++ww) off += wcnt[ww][r];
  locpos[n] = off + p_in_wave;
  if (tid < 8)
    blockcnt[blockIdx.x * 8 + tid] =
        wcnt[0][tid] + wcnt[1][tid] + wcnt[2][tid] + wcnt[3][tid];
}

__global__ __launch_bounds__(64) void scan_base_kernel(
    const int* __restrict__ blockcnt, int* __restrict__ blockbase,
    int* __restrict__ cnt_kept, float* __restrict__ counts_out,
    float* __restrict__ ndrop_out) {
  __shared__ int tot[8];
  int e = threadIdx.x;
  if (e < 8) {
    int run = 0;
    for (int b = 0; b < 64; ++b) { blockbase[b * 8 + e] = run; run += blockcnt[b * 8 + e]; }
    counts_out[e] = (float)run;
    cnt_kept[e] = run < CAPE ? run : CAPE;
    tot[e] = run;
  }
  __syncthreads();
  if (e == 0) {
    int nd = 0;
    for (int i = 0; i < 8; ++i) nd += (tot[i] > CAPE) ? (tot[i] - CAPE) : 0;
    ndrop_out[0] = (float)nd;
  }
}

__global__ __launch_bounds__(256) void scan_fill_kernel(
    const int* __restrict__ routes, const int* __restrict__ locpos,
    const int* __restrict__ blockbase, int* __restrict__ pos,
    int* __restrict__ toklist) {
  int n = blockIdx.x * 256 + threadIdx.x;
  int r = routes[n];
  int pn = blockbase[blockIdx.x * 8 + r] + locpos[n];
  pos[n] = pn;
  if (pn < CAPE) toklist[r * CAPE + pn] = n;
}

// ---------------- transpose + fp32->bf16 convert: out[C][R] = bf16(in[R][C]), per expert z
__global__ __launch_bounds__(256) void transpose_bf16_kernel(
    const float* __restrict__ in, ushort* __restrict__ out, int R, int C) {
  __shared__ float T[64][65];
  int e = blockIdx.z;
  const float* src = in + (size_t)e * R * C;
  ushort* dst = out + (size_t)e * R * C;
  int c0 = blockIdx.x * 64, r0 = blockIdx.y * 64;
  int tid = threadIdx.x;
#pragma unroll
  for (int i = 0; i < 4; ++i) {
    int idx = tid + i * 256;
    int r = idx >> 4, c4 = (idx & 15) * 4;
    float4 t = *reinterpret_cast<const float4*>(&src[(size_t)(r0 + r) * C + c0 + c4]);
    T[r][c4] = t.x; T[r][c4 + 1] = t.y; T[r][c4 + 2] = t.z; T[r][c4 + 3] = t.w;
  }
  __syncthreads();
  int n = tid >> 2, kg = (tid & 3) * 16;
  uint4 o[2];
  uint* ow = reinterpret_cast<uint*>(o);
#pragma unroll
  for (int wdx = 0; wdx < 8; ++wdx)
    ow[wdx] = (unsigned)f2bf(T[kg + 2 * wdx][n]) | ((unsigned)f2bf(T[kg + 2 * wdx + 1][n]) << 16);
  *reinterpret_cast<uint4*>(&dst[(size_t)(c0 + n) * R + r0 + kg]) = o[0];
  *reinterpret_cast<uint4*>(&dst[(size_t)(c0 + n) * R + r0 + kg + 8]) = o[1];
}

// ---------------- MoE GEMM1: 256x128 tile, 8 waves, XCD swizzle
__global__ __launch_bounds__(512) void moe_gemm1_kernel(
    const ushort* __restrict__ x1bf, const ushort* __restrict__ W1t,
    const float* __restrict__ b1, const int* __restrict__ toklist,
    const int* __restrict__ cnt_kept, ushort* __restrict__ H, int f0base) {
  __shared__ __align__(16) ushort As[256][64];
  __shared__ __align__(16) ushort Bs[128][64];
  __shared__ int toks[256];
  int nwg = gridDim.x * gridDim.y * gridDim.z;
  int linear = blockIdx.x + gridDim.x * (blockIdx.y + gridDim.y * blockIdx.z);
  int swz = (linear % 8) * (nwg / 8) + linear / 8;
  int bx = swz % gridDim.x;
  int tmp = swz / gridDim.x;
  int by = tmp % gridDim.y;
  int e = tmp / gridDim.y;
  int cnt = cnt_kept[e];
  int m0 = by * 256;
  if (m0 >= cnt) return;
  int n0 = bx * 128;
  int tid = threadIdx.x;
  int wave = tid >> 6, lane = tid & 63;
  int wm = wave >> 1, wn = wave & 1;
  int c16 = lane & 15, g = lane >> 4;

  for (int i = tid; i < 256; i += 512) {
    int idx = m0 + i;
    toks[i] = toklist[e * CAPE + (idx < cnt ? idx : 0)];
  }
  __syncthreads();

  int row_in = lane >> 3, k8 = (lane & 7) * 8;
  size_t atok[4];
#pragma unroll
  for (int i = 0; i < 4; ++i)
    atok[i] = (size_t)toks[wave * 32 + i * 8 + row_in] * DMODEL;
  const ushort* Wbase = W1t + ((size_t)e * DFF + f0base + n0) * DMODEL;
  f32x4 acc[4][4] = {};

  for (int k0 = 0; k0 < DMODEL; k0 += 64) {
#pragma unroll
    for (int i = 0; i < 4; ++i) {
      int rowa = wave * 32 + i * 8;
      gload_lds16(x1bf + atok[i] + k0 + k8, &As[rowa][0]);
    }
#pragma unroll
    for (int i = 0; i < 2; ++i) {
      int rowb = wave * 16 + i * 8;
      gload_lds16(Wbase + (size_t)(rowb + row_in) * DMODEL + k0 + k8, &Bs[rowb][0]);
    }
    __syncthreads();
#pragma unroll
    for (int ks = 0; ks < 2; ++ks) {
      bf16x8 af[4], bfr[4];
#pragma unroll
      for (int mt = 0; mt < 4; ++mt)
        af[mt] = *reinterpret_cast<bf16x8*>(&As[wm * 64 + mt * 16 + c16][ks * 32 + g * 8]);
#pragma unroll
      for (int nt = 0; nt < 4; ++nt)
        bfr[nt] = *reinterpret_cast<bf16x8*>(&Bs[wn * 64 + nt * 16 + c16][ks * 32 + g * 8]);
#pragma unroll
      for (int mt = 0; mt < 4; ++mt)
#pragma unroll
        for (int nt = 0; nt < 4; ++nt)
          acc[mt][nt] = __builtin_amdgcn_mfma_f32_16x16x32_bf16(af[mt], bfr[nt], acc[mt][nt], 0, 0, 0);
    }
    __syncthreads();
  }
  int rowq = g * 4;
#pragma unroll
  for (int mt = 0; mt < 4; ++mt) {
#pragma unroll
    for (int i = 0; i < 4; ++i) {
      int mm = wm * 64 + mt * 16 + rowq + i;
      if (m0 + mm < cnt) {
        size_t hb = (size_t)toks[mm] * 1024;
#pragma unroll
        for (int nt = 0; nt < 4; ++nt) {
          int col = n0 + wn * 64 + nt * 16 + c16;
          float v = acc[mt][nt][i] + b1[e * DFF + f0base + col];
          H[hb + col] = f2bf(fmaxf(v, 0.f));
        }
      }
    }
  }
}

// ---------------- MoE GEMM2: 256x128 tile, 8 waves, XCD swizzle (bf16 ybuf)
__global__ __launch_bounds__(512) void moe_gemm2_kernel(
    const ushort* __restrict__ H, const ushort* __restrict__ W2t,
    const float* __restrict__ b2, const int* __restrict__ toklist,
    const int* __restrict__ cnt_kept, ushort* __restrict__ ybuf,
    int f0base, int addprev) {
  __shared__ __align__(16) ushort As[256][64];
  __shared__ __align__(16) ushort Bs[128][64];
  __shared__ int toks[256];
  int nwg = gridDim.x * gridDim.y * gridDim.z;
  int linear = blockIdx.x + gridDim.x * (blockIdx.y + gridDim.y * blockIdx.z);
  int swz = (linear % 8) * (nwg / 8) + linear / 8;
  int bx = swz % gridDim.x;
  int tmp = swz / gridDim.x;
  int by = tmp % gridDim.y;
  int e = tmp / gridDim.y;
  int cnt = cnt_kept[e];
  int m0 = by * 256;
  if (m0 >= cnt) return;
  int n0 = bx * 128;
  int tid = threadIdx.x;
  int wave = tid >> 6, lane = tid & 63;
  int wm = wave >> 1, wn = wave & 1;
  int c16 = lane & 15, g = lane >> 4;

  for (int i = tid; i < 256; i += 512) {
    int idx = m0 + i;
    toks[i] = toklist[e * CAPE + (idx < cnt ? idx : 0)];
  }
  __syncthreads();

  int row_in = lane >> 3, k8 = (lane & 7) * 8;
  size_t atok[4];
#pragma unroll
  for (int i = 0; i < 4; ++i)
    atok[i] = (size_t)toks[wave * 32 + i * 8 + row_in] * 1024;
  const ushort* Wbase = W2t + ((size_t)e * DMODEL + n0) * DFF + f0base;
  f32x4 acc[4][4] = {};

  for (int k0 = 0; k0 < 1024; k0 += 64) {
#pragma unroll
    for (int i = 0; i < 4; ++i) {
      int rowa = wave * 32 + i * 8;
      gload_lds16(H + atok[i] + k0 + k8, &As[rowa][0]);
    }
#pragma unroll
    for (int i = 0; i < 2; ++i) {
      int rowb = wave * 16 + i * 8;
      gload_lds16(Wbase + (size_t)(rowb + row_in) * DFF + k0 + k8, &Bs[rowb][0]);
    }
    __syncthreads();
#pragma unroll
    for (int ks = 0; ks < 2; ++ks) {
      bf16x8 af[4], bfr[4];
#pragma unroll
      for (int mt = 0; mt < 4; ++mt)
        af[mt] = *reinterpret_cast<bf16x8*>(&As[wm * 64 + mt * 16 + c16][ks * 32 + g * 8]);
#pragma unroll
      for (int nt = 0; nt < 4; ++nt)
        bfr[nt] = *reinterpret_cast<bf16x8*>(&Bs[wn * 64 + nt * 16 + c16][ks * 32 + g * 8]);
#pragma unroll
      for (int mt = 0; mt < 4; ++mt)
#pragma unroll
        for (int nt = 0; nt < 4; ++nt)
          acc[mt][nt] = __builtin_amdgcn_mfma_f32_16x16x32_bf16(af[mt], bfr[nt], acc[mt][nt], 0, 0, 0);
    }
    __syncthreads();
  }
  int rowq = g * 4;
#pragma unroll
  for (int mt = 0; mt < 4; ++mt) {
#pragma unroll
    for (int i = 0; i < 4; ++i) {
      int mm = wm * 64 + mt * 16 + rowq + i;
      if (m0 + mm < cnt) {
        size_t yb = (size_t)toks[mm] * DMODEL;
#pragma unroll
        for (int nt = 0; nt < 4; ++nt) {
          int col = n0 + wn * 64 + nt * 16 + c16;
          float v = acc[mt][nt][i];
          v += addprev ? bf2f(ybuf[yb + col]) : b2[e * DMODEL + col];
          ybuf[yb + col] = f2bf(v);
        }
      }
    }
  }
}

// ---------------- combine + final LayerNorm (ybuf bf16)
__global__ __launch_bounds__(256) void final_ln_kernel(
    const float* __restrict__ x1, const ushort* __restrict__ ybuf,
    const int* __restrict__ pos, const float* __restrict__ rpm,
    const float* __restrict__ g, const float* __restrict__ beta,
    float* __restrict__ out) {
  __shared__ float red[4];
  int row = blockIdx.x, tid = threadIdx.x;
  size_t base = (size_t)row * DMODEL;
  bool kept = pos[row] < CAPE;
  float scale = rpm[row];
  float a0 = x1[base + tid], a1 = x1[base + tid + 256];
  float y0 = (kept ? bf2f(ybuf[base + tid])       : a0) * scale;
  float y1 = (kept ? bf2f(ybuf[base + tid + 256]) : a1) * scale;
  float v0 = a0 + y0, v1 = a1 + y1;
  float s = block_reduce_sum(v0 + v1, red);
  float mean = s * (1.0f / DMODEL);
  float d0 = v0 - mean, d1 = v1 - mean;
  float vs = block_reduce_sum(d0 * d0 + d1 * d1, red);
  float inv = rsqrtf(vs * (1.0f / DMODEL) + LNEPS);
  out[base + tid]       = d0 * inv * g[tid] + beta[tid];
  out[base + tid + 256] = d1 * inv * g[tid + 256] + beta[tid + 256];
}

__global__ void zero_small_kernel(float* route_prob) {
  if (threadIdx.x < 8) route_prob[threadIdx.x] = 0.f;
}

extern "C" void kernel_launch(void* const* d_in, const int* in_sizes, int n_in,
                              void* d_out, int out_size, void* d_ws, size_t ws_size,
                              hipStream_t stream) {
  const float* x    = (const float*)d_in[0];
  const float* Wq   = (const float*)d_in[1];
  const float* bq   = (const float*)d_in[2];
  const float* Wk   = (const float*)d_in[3];
  const float* bk   = (const float*)d_in[4];
  const float* Wv   = (const float*)d_in[5];
  const float* bv   = (const float*)d_in[6];
  const float* Wo   = (const float*)d_in[7];
  const float* bo   = (const float*)d_in[8];
  const float* ln1g = (const float*)d_in[9];
  const float* ln1b = (const float*)d_in[10];
  const float* Wr   = (const float*)d_in[11];
  const float* br   = (const float*)d_in[12];
  const float* W1   = (const float*)d_in[13];
  const float* b1   = (const float*)d_in[14];
  const float* W2   = (const float*)d_in[15];
  const float* b2   = (const float*)d_in[16];
  const float* ln2g = (const float*)d_in[17];
  const float* ln2b = (const float*)d_in[18];

  float* ws = (float*)d_ws;
  const size_t ND = (size_t)NTOK * DMODEL;
  float* qb   = ws;
  float* kb   = ws + ND;
  float* vb   = ws + 2 * ND;
  float* out  = (float*)d_out;
  float* ctxb = out;            // d_out region as ctx scratch (pre-MoE)
  float* tmpb = qb;             // O-proj output (q consumed by attention)
  float* x1b  = vb;             // post-LN1 fp32 (v consumed by attention)
  ushort* ybuf  = (ushort*)kb;            // FFN output, bf16
  ushort* x1bfb = (ushort*)kb + ND;       // bf16 x1
  ushort* Hbuf = (ushort*)qb;   // half-F H buffer
  ushort* W1th = (ushort*)out;
  ushort* W2th = W1th + (size_t)NEXP * DFF * DMODEL;
  const size_t WSZ = (size_t)3 * DMODEL * DMODEL;
  ushort* Wq3 = (ushort*)out;
  ushort* Wk3 = Wq3 + WSZ;
  ushort* Wv3 = Wk3 + WSZ;
  ushort* Wo3 = (ushort*)kb;
  int* routes   = (int*)(ws + 3 * ND);
  int* posb     = routes + NTOK;
  int* toklist  = posb + NTOK;
  int* cnt_kept = toklist + NEXP * CAPE;
  int* locpos    = (int*)qb;
  int* blockcnt  = locpos + NTOK;
  int* blockbase = blockcnt + 512;

  float* counts_out = out + ND;
  float* rp_out     = counts_out + 8;
  float* nd_out     = rp_out + 8;
  float* rpm_out    = nd_out + 1;

  zero_small_kernel<<<1, 64, 0, stream>>>(rp_out);

  dim3 wg(8, 8);
  wsplit3_kernel<<<wg, 256, 0, stream>>>(Wq, Wq3, DMODEL, DMODEL);
  wsplit3_kernel<<<wg, 256, 0, stream>>>(Wk, Wk3, DMODEL, DMODEL);
  wsplit3_kernel<<<wg, 256, 0, stream>>>(Wv, Wv3, DMODEL, DMODEL);

  dim3 gg(DMODEL / 128, NTOK / 128);
  gemm_split3_kernel<<<gg, 256, 0, stream>>>(x, Wq3, bq, qb, NTOK, DMODEL, DMODEL);
  gemm_split3_kernel<<<gg, 256, 0, stream>>>(x, Wk3, bk, kb, NTOK, DMODEL, DMODEL);
  gemm_split3_kernel<<<gg, 256, 0, stream>>>(x, Wv3, bv, vb, NTOK, DMODEL, DMODEL);

  attn_kernel<<<BATCH * NHEAD * (SEQ / 256), 512, 0, stream>>>(qb, kb, vb, ctxb);

  wsplit3_kernel<<<wg, 256, 0, stream>>>(Wo, Wo3, DMODEL, DMODEL);
  gemm_split3_kernel<<<gg, 256, 0, stream>>>(ctxb, Wo3, bo, tmpb, NTOK, DMODEL, DMODEL);
  add_ln_kernel<<<NTOK, 256, 0, stream>>>(x, tmpb, ln1g, ln1b, x1b, x1bfb);

  transpose_bf16_kernel<<<dim3(DFF / 64, DMODEL / 64, NEXP), 256, 0, stream>>>(
      W1, W1th, DMODEL, DFF);
  transpose_bf16_kernel<<<dim3(DMODEL / 64, DFF / 64, NEXP), 256, 0, stream>>>(
      W2, W2th, DFF, DMODEL);

  router_kernel<<<NTOK / 4, 256, 0, stream>>>(x1b, Wr, br, routes, rpm_out, rp_out);
  scan_count_kernel<<<64, 256, 0, stream>>>(routes, locpos, blockcnt);
  scan_base_kernel<<<1, 64, 0, stream>>>(blockcnt, blockbase, cnt_kept, counts_out, nd_out);
  scan_fill_kernel<<<64, 256, 0, stream>>>(routes, locpos, blockbase, posb, toklist);

  dim3 g1(8, CAPE / 256, NEXP);
  dim3 g2(4, CAPE / 256, NEXP);
  moe_gemm1_kernel<<<g1, 512, 0, stream>>>(x1bfb, W1th, b1, toklist, cnt_kept, Hbuf, 0);
  moe_gemm2_kernel<<<g2, 512, 0, stream>>>(Hbuf, W2th, b2, toklist, cnt_kept, ybuf, 0, 0);
  moe_gemm1_kernel<<<g1, 512, 0, stream>>>(x1bfb, W1th, b1, toklist, cnt_kept, Hbuf, 1024);
  moe_gemm2_kernel<<<g2, 512, 0, stream>>>(Hbuf, W2th, b2, toklist, cnt_kept, ybuf, 1024, 1);

  final_ln_kernel<<<NTOK, 256, 0, stream>>>(x1b, ybuf, posb, rpm_out, ln2g, ln2b, out);
}